// Round 7
// baseline (171.025 us; speedup 1.0000x reference)
//
#include <hip/hip_runtime.h>

#define HW 16384
#define C 128

typedef __attribute__((ext_vector_type(8))) short short8;
typedef __attribute__((ext_vector_type(4))) float f32x4;
typedef __attribute__((ext_vector_type(2))) float f32x2;
typedef __attribute__((ext_vector_type(16))) int v16i;

__device__ __forceinline__ unsigned short f2bf(float f) {
  union { float f; unsigned u; } v; v.f = f;
  return (unsigned short)((v.u + 0x7fffu + ((v.u >> 16) & 1u)) >> 16);
}
#if __has_builtin(__builtin_amdgcn_cvt_pk_bf16_f32)
typedef __attribute__((ext_vector_type(2))) __bf16 bf16x2;
__device__ __forceinline__ unsigned pk2(float a, float b) {   // HW RNE pack
  union { bf16x2 v; unsigned u; } cv;
  cv.v = __builtin_amdgcn_cvt_pk_bf16_f32(a, b);
  return cv.u;
}
#else
__device__ __forceinline__ unsigned pk2(float a, float b) {   // SW RNE pack
  return (unsigned)f2bf(a) | ((unsigned)f2bf(b) << 16);
}
#endif
__device__ __forceinline__ unsigned short f2bf1(float a) {
  return (unsigned short)(pk2(a, a) & 0xffffu);
}
__device__ __forceinline__ float bflo(unsigned w) {
  union { unsigned u; float f; } v; v.u = w << 16; return v.f;
}
__device__ __forceinline__ float bfhi(unsigned w) {
  union { unsigned u; float f; } v; v.u = w & 0xffff0000u; return v.f;
}
__device__ __forceinline__ float asf(int u) {
  union { int u; float f; } v; v.u = u; return v.f;
}

// ---------------- Kernel 0: precompute Mt = C^-0.5 * Wk^T Wq, P = Wproj @ Wv,
// both stored bf16 with the fragment XOR swizzle pre-applied, plus pw/pi.
__global__ __launch_bounds__(128) void k_prep(const float* __restrict__ w_qkv,
                                              const float* __restrict__ w_proj,
                                              const float* __restrict__ delta,
                                              unsigned short* __restrict__ Mt,
                                              unsigned short* __restrict__ Pm,
                                              float* __restrict__ pw,
                                              int* __restrict__ pi) {
  const int bid = blockIdx.x;
  const int t = threadIdx.x;
  if (bid == 256) {
    if (t < 8) {
      float s0 = tanhf(delta[t * 2 + 0]) * 4.0f;  // col shift (x)
      float s1 = tanhf(delta[t * 2 + 1]) * 4.0f;  // row shift (y)
      float f0 = floorf(s0), f1 = floorf(s1);
      pi[2 * t + 0] = (int)f0;
      pi[2 * t + 1] = (int)f1;
      float fx = s0 - f0, fy = s1 - f1;
      pw[4 * t + 0] = (1.0f - fx) * (1.0f - fy);
      pw[4 * t + 1] = fx * (1.0f - fy);
      pw[4 * t + 2] = (1.0f - fx) * fy;
      pw[4 * t + 3] = fx * fy;
    }
    return;
  }
  const int R = bid & 127;
  float acc = 0.0f;
  if (bid < 128) {                         // Mt row R
    const float* wq = w_qkv;               // Wq[j][c]
    const float* wk = w_qkv + 128 * 128;   // Wk[j][o]
    #pragma unroll 16
    for (int j = 0; j < 128; ++j)
      acc += wk[j * 128 + R] * wq[j * 128 + t];   // wk: scalar, wq: coalesced
    acc *= 0.08838834764831845f;           // fold C^-0.5 into the logits
    Mt[R * 128 + (t ^ ((R & 7) << 3))] = f2bf1(acc);
  } else {                                 // P row R
    const float* wv = w_qkv + 2 * 128 * 128;  // Wv[j][c]
    const float* wp = w_proj + (size_t)R * 128;  // Wproj[R][j]
    #pragma unroll 16
    for (int j = 0; j < 128; ++j)
      acc += wp[j] * wv[j * 128 + t];
    Pm[R * 128 + (t ^ ((R & 7) << 3))] = f2bf1(acc);
  }
}

// ---------------- Kernel 1: xq = bf16(x) transposed [pix][ch] ----------------
// Pure transpose/convert, 32-pixel tiles (2048 blocks, 8 KB LDS). float4 loads
// along pixels (4x fewer VMEM than dword), coalesced uint4 stores.
__global__ __launch_bounds__(256) void k_xq(const float* __restrict__ x,
                                            unsigned* __restrict__ xq) {
  __shared__ __align__(16) unsigned short Xs[32 * 128];  // 8 KB
  const int t = threadIdx.x;
  const int gpix0 = blockIdx.x * 32;
  const int b = gpix0 >> 14;
  const int hw0 = gpix0 & (HW - 1);
  const float* xb = x + (size_t)b * C * HW + hw0;

  #pragma unroll
  for (int i = 0; i < 4; ++i) {
    int idx = i * 256 + t;
    int c = idx >> 3;           // 0..127
    int p4 = idx & 7;           // float4 group over 32 pixels
    float4 v = *(const float4*)(xb + (size_t)c * HW + p4 * 4);
    int p0 = p4 * 4;
    Xs[(p0 + 0) * 128 + (c ^ (((p0 + 0) & 7) << 3))] = f2bf1(v.x);
    Xs[(p0 + 1) * 128 + (c ^ (((p0 + 1) & 7) << 3))] = f2bf1(v.y);
    Xs[(p0 + 2) * 128 + (c ^ (((p0 + 2) & 7) << 3))] = f2bf1(v.z);
    Xs[(p0 + 3) * 128 + (c ^ (((p0 + 3) & 7) << 3))] = f2bf1(v.w);
  }
  __syncthreads();
  #pragma unroll
  for (int i = 0; i < 2; ++i) {
    int idx = i * 256 + t;
    int pix = idx >> 4;
    int c8 = (idx & 15) * 8;
    uint4 v = *(const uint4*)&Xs[pix * 128 + (c8 ^ ((pix & 7) << 3))];
    *(uint4*)&xq[(size_t)(gpix0 + pix) * 64 + (c8 >> 1)] = v;
  }
}

// ---------------- Kernel 2: fused q'-GEMM + gather-attention + proj-GEMM -----
// 16 pixels per 512-thread block (4096 blocks). Phases:
//  (a) stage own x~ tile (4 KB LDS, swizzled)
//  (b) q' = Mt x~ : each wave owns a 16-channel block, 4 MFMAs (Mt from L1-hot
//      global, pre-swizzled rows) -> Qt LDS
//  (c) gather + softmax (R6-verified: 2 pix/wave, bf16 uint2 corners) -> Ot LDS
//  (d) out = x + P o : 4 MFMAs/wave (Pm from global), fp32 residual, direct store
__global__ __launch_bounds__(512) void k_attn(const unsigned* __restrict__ xq,
                                              const int* __restrict__ psf,
                                              const int* __restrict__ pwu,
                                              const unsigned short* __restrict__ Mt,
                                              const unsigned short* __restrict__ Pm,
                                              const float* __restrict__ x,
                                              float* __restrict__ out) {
  __shared__ __align__(16) unsigned short Xt[16 * 128];  // 4 KB
  __shared__ __align__(16) unsigned short Qt[16 * 128];  // 4 KB
  __shared__ __align__(16) unsigned short Ot[16 * 128];  // 4 KB
  const int t = threadIdx.x;
  const int wave = t >> 6, lane = t & 63;
  const int rsel = lane & 15, quad = lane >> 4;
  const int li = t & 31, half = (t >> 5) & 1;
  const int gid = blockIdx.x;
  const int b = gid & 3;                     // batch -> XCD spread
  const int grp = gid >> 2;
  const int gpix0 = grp << 4;                // hw offset within batch
  const size_t spix0 = ((size_t)b << 14) + gpix0;

  // (a) stage own x~ tile: 256 uint4
  if (t < 256) {
    int pix = t >> 4;
    int c8 = (t & 15) * 8;
    uint4 v = *(const uint4*)((const unsigned short*)xq + (spix0 + pix) * 128 + c8);
    *(uint4*)&Xt[pix * 128 + (c8 ^ ((pix & 7) << 3))] = v;
  }

  // scalar tables: pw[0..15], pw[16..31], pi[0..15]
  v16i w0, w1, tpi;
  asm volatile(
      "s_load_dwordx16 %0, %3, 0\n\t"
      "s_load_dwordx16 %1, %3, 64\n\t"
      "s_load_dwordx16 %2, %3, 128\n\t"
      "s_waitcnt lgkmcnt(0)"
      : "=&s"(w0), "=&s"(w1), "=&s"(tpi)
      : "s"(pwu));
  __syncthreads();

  // (b) q' = Mt(16-row slice per wave) x~tile : D och=16w+quad*4+r, pix=rsel
  {
    f32x4 qacc = (f32x4){0.f, 0.f, 0.f, 0.f};
    const unsigned short* MtW = Mt + (size_t)(wave * 16) * 128;
    #pragma unroll
    for (int ks = 0; ks < 4; ++ks) {
      const int koff = ks * 32 + quad * 8;
      short8 afr = *(const short8*)&MtW[rsel * 128 + (koff ^ ((rsel & 7) << 3))];
      short8 bfr = *(const short8*)&Xt[rsel * 128 + (koff ^ ((rsel & 7) << 3))];
      qacc = __builtin_amdgcn_mfma_f32_16x16x32_bf16(afr, bfr, qacc, 0, 0, 0);
    }
    #pragma unroll
    for (int r = 0; r < 4; ++r) {
      int ch = wave * 16 + quad * 4 + r;
      Qt[rsel * 128 + (ch ^ ((rsel & 7) << 3))] = f2bf1(qacc[r]);
    }
  }
  __syncthreads();

  // (c) gather + softmax: 2 pixels/wave, lane owns 4 channels
  const int pixl = (wave << 1) + half;       // 0..15
  {
    const int4* pr = (const int4*)(psf + (spix0 + pixl) * 16);
    int4 a0 = pr[0], a1 = pr[1], a2 = pr[2], a3 = pr[3];
    int va[16] = {a0.x, a0.y, a0.z, a0.w, a1.x, a1.y, a1.z, a1.w,
                  a2.x, a2.y, a2.z, a2.w, a3.x, a3.y, a3.z, a3.w};

    const uint2 qp = *(const uint2*)&Qt[pixl * 128 + ((4 * li) ^ ((pixl & 7) << 3))];
    const float q0 = bflo(qp.x), q1 = bfhi(qp.x);
    const float q2 = bflo(qp.y), q3 = bfhi(qp.y);

    const unsigned* xB = xq + (((size_t)b << 14) << 6);  // batch base (dwords)

    float s0[8], s1[8], s2[8], s3[8], dk[8];
    #pragma unroll
    for (int k = 0; k < 8; ++k) {
      const int x0 = va[2 * k + 0] + tpi[2 * k + 0];
      const int y0 = va[2 * k + 1] + tpi[2 * k + 1];
      float t0 = 0.f, t1 = 0.f, t2 = 0.f, t3 = 0.f;
      #pragma unroll
      for (int cn = 0; cn < 4; ++cn) {
        const int xi = x0 + (cn & 1);
        const int yi = y0 + (cn >> 1);
        const bool valid = ((unsigned)xi <= 127u) & ((unsigned)yi <= 127u);
        const int xc = min(max(xi, 0), 127);   // v_med3_i32
        const int yc = min(max(yi, 0), 127);
        const int widx = k * 4 + cn;
        const float wv = valid ? asf(widx < 16 ? w0[widx & 15] : w1[widx & 15]) : 0.0f;
        const uint2 w2 = *(const uint2*)&xB[((size_t)((yc << 7) + xc) << 6) + 2 * li];
        t0 = fmaf(bflo(w2.x), wv, t0); t1 = fmaf(bfhi(w2.x), wv, t1);
        t2 = fmaf(bflo(w2.y), wv, t2); t3 = fmaf(bfhi(w2.y), wv, t3);
      }
      s0[k] = t0; s1[k] = t1; s2[k] = t2; s3[k] = t3;
      dk[k] = fmaf(q0, t0, fmaf(q1, t1, fmaf(q2, t2, q3 * t3)));
    }
    #pragma unroll
    for (int off = 16; off > 0; off >>= 1) {
      #pragma unroll
      for (int k = 0; k < 8; ++k) dk[k] += __shfl_xor(dk[k], off);
    }
    float m = dk[0];
    #pragma unroll
    for (int k = 1; k < 8; ++k) m = fmaxf(m, dk[k]);
    float den = 0.0f;
    #pragma unroll
    for (int k = 0; k < 8; ++k) { dk[k] = __expf(dk[k] - m); den += dk[k]; }
    const float inv = 1.0f / den;
    float o0 = 0.f, o1 = 0.f, o2 = 0.f, o3 = 0.f;
    #pragma unroll
    for (int k = 0; k < 8; ++k) {
      const float pk = dk[k] * inv;
      o0 = fmaf(pk, s0[k], o0); o1 = fmaf(pk, s1[k], o1);
      o2 = fmaf(pk, s2[k], o2); o3 = fmaf(pk, s3[k], o3);
    }
    *(uint2*)&Ot[pixl * 128 + ((4 * li) ^ ((pixl & 7) << 3))] =
        make_uint2(pk2(o0, o1), pk2(o2, o3));
  }
  __syncthreads();

  // (d) out = x + P o : D och=16w+quad*4+r, pix=rsel; fp32 residual
  {
    f32x4 pacc = (f32x4){0.f, 0.f, 0.f, 0.f};
    const unsigned short* PmW = Pm + (size_t)(wave * 16) * 128;
    #pragma unroll
    for (int ks = 0; ks < 4; ++ks) {
      const int koff = ks * 32 + quad * 8;
      short8 afr = *(const short8*)&PmW[rsel * 128 + (koff ^ ((rsel & 7) << 3))];
      short8 bfr = *(const short8*)&Ot[rsel * 128 + (koff ^ ((rsel & 7) << 3))];
      pacc = __builtin_amdgcn_mfma_f32_16x16x32_bf16(afr, bfr, pacc, 0, 0, 0);
    }
    #pragma unroll
    for (int r = 0; r < 4; ++r) {
      int och = wave * 16 + quad * 4 + r;
      size_t addr = ((size_t)b * C + och) * HW + gpix0 + rsel;
      out[addr] = x[addr] + pacc[r];
    }
  }
}

extern "C" void kernel_launch(void* const* d_in, const int* in_sizes, int n_in,
                              void* d_out, int out_size, void* d_ws, size_t ws_size,
                              hipStream_t stream) {
  const float* x      = (const float*)d_in[0];
  const int*   psf    = (const int*)d_in[1];
  const float* delta  = (const float*)d_in[2];
  const float* w_qkv  = (const float*)d_in[3];
  const float* w_proj = (const float*)d_in[4];
  float* out = (float*)d_out;

  unsigned* xq = (unsigned*)d_ws;                      // 16 MB bf16 x~ [pix][64dw]
  unsigned short* Mt = (unsigned short*)(xq + (size_t)4 * HW * 64);  // 32 KB
  unsigned short* Pm = Mt + 16384;                     // 32 KB
  float* pw = (float*)(Pm + 16384);                    // 32 floats
  int*   pi = (int*)(pw + 32);                         // 16 ints (contiguous!)

  k_prep<<<dim3(257), 128, 0, stream>>>(w_qkv, w_proj, delta, Mt, Pm, pw, pi);
  k_xq<<<dim3(2048), 256, 0, stream>>>(x, xq);
  k_attn<<<dim3(4096), 512, 0, stream>>>(xq, psf, (const int*)pw, Mt, Pm, x, out);
}

// Round 8
// 149.616 us; speedup vs baseline: 1.1431x; 1.1431x over previous
//
#include <hip/hip_runtime.h>

#define HW 16384
#define C 128

typedef __attribute__((ext_vector_type(8))) short short8;
typedef __attribute__((ext_vector_type(4))) float f32x4;
typedef __attribute__((ext_vector_type(2))) float f32x2;
typedef __attribute__((ext_vector_type(16))) int v16i;

__device__ __forceinline__ unsigned short f2bf(float f) {
  union { float f; unsigned u; } v; v.f = f;
  return (unsigned short)((v.u + 0x7fffu + ((v.u >> 16) & 1u)) >> 16);
}
#if __has_builtin(__builtin_amdgcn_cvt_pk_bf16_f32)
typedef __attribute__((ext_vector_type(2))) __bf16 bf16x2;
__device__ __forceinline__ unsigned pk2(float a, float b) {   // HW RNE pack
  union { bf16x2 v; unsigned u; } cv;
  cv.v = __builtin_amdgcn_cvt_pk_bf16_f32(a, b);
  return cv.u;
}
#else
__device__ __forceinline__ unsigned pk2(float a, float b) {   // SW RNE pack
  return (unsigned)f2bf(a) | ((unsigned)f2bf(b) << 16);
}
#endif
__device__ __forceinline__ unsigned short f2bf1(float a) {
  return (unsigned short)(pk2(a, a) & 0xffffu);
}
__device__ __forceinline__ float bflo(unsigned w) {
  union { unsigned u; float f; } v; v.u = w << 16; return v.f;
}
__device__ __forceinline__ float bfhi(unsigned w) {
  union { unsigned u; float f; } v; v.u = w & 0xffff0000u; return v.f;
}
__device__ __forceinline__ float asf(int u) {
  union { int u; float f; } v; v.u = u; return v.f;
}
__device__ __forceinline__ float bf2f(unsigned short h) {
  union { unsigned u; float f; } v; v.u = ((unsigned)h) << 16; return v.f;
}

// ---------------- Kernel 0: precompute Mt = C^-0.5 * Wk^T Wq, P = Wproj @ Wv,
// both stored bf16 with the fragment XOR swizzle pre-applied, plus pw/pi.
__global__ __launch_bounds__(128) void k_prep(const float* __restrict__ w_qkv,
                                              const float* __restrict__ w_proj,
                                              const float* __restrict__ delta,
                                              unsigned short* __restrict__ Mt,
                                              unsigned short* __restrict__ Pm,
                                              float* __restrict__ pw,
                                              int* __restrict__ pi) {
  const int bid = blockIdx.x;
  const int t = threadIdx.x;
  if (bid == 256) {
    if (t < 8) {
      float s0 = tanhf(delta[t * 2 + 0]) * 4.0f;  // col shift (x)
      float s1 = tanhf(delta[t * 2 + 1]) * 4.0f;  // row shift (y)
      float f0 = floorf(s0), f1 = floorf(s1);
      pi[2 * t + 0] = (int)f0;
      pi[2 * t + 1] = (int)f1;
      float fx = s0 - f0, fy = s1 - f1;
      pw[4 * t + 0] = (1.0f - fx) * (1.0f - fy);
      pw[4 * t + 1] = fx * (1.0f - fy);
      pw[4 * t + 2] = (1.0f - fx) * fy;
      pw[4 * t + 3] = fx * fy;
    }
    return;
  }
  const int R = bid & 127;
  float acc = 0.0f;
  if (bid < 128) {                         // Mt row R
    const float* wq = w_qkv;               // Wq[j][c]
    const float* wk = w_qkv + 128 * 128;   // Wk[j][o]
    #pragma unroll 16
    for (int j = 0; j < 128; ++j)
      acc += wk[j * 128 + R] * wq[j * 128 + t];   // wk: scalar, wq: coalesced
    acc *= 0.08838834764831845f;           // fold C^-0.5 into the logits
    Mt[R * 128 + (t ^ ((R & 7) << 3))] = f2bf1(acc);
  } else {                                 // P row R
    const float* wv = w_qkv + 2 * 128 * 128;  // Wv[j][c]
    const float* wp = w_proj + (size_t)R * 128;  // Wproj[R][j]
    #pragma unroll 16
    for (int j = 0; j < 128; ++j)
      acc += wp[j] * wv[j * 128 + t];
    Pm[R * 128 + (t ^ ((R & 7) << 3))] = f2bf1(acc);
  }
}

// ---------------- Kernel 1: q' = x * Mt GEMM + bf16 transposed copy of x -----
// 128-pixel tiles. Only Xs in LDS (32 KB -> 4-5 blocks/CU, was 2 with Ws).
// Mt fragments read directly from global inside the ks loop (L1/L2-hot,
// identical bits to the old LDS copy). q' repacked via Xs for uint4 stores.
__global__ __launch_bounds__(256) void k_qx(const float* __restrict__ x,
                                            const unsigned short* __restrict__ Mt,
                                            unsigned short* __restrict__ qb,
                                            unsigned* __restrict__ xq) {
  __shared__ __align__(16) unsigned short Xs[128 * 128];  // 32 KB
  const int t = threadIdx.x;
  const int gpix0 = blockIdx.x * 128;
  const int b = gpix0 >> 14;
  const int hw0 = gpix0 & (HW - 1);

  // stage Xs [pix][k] bf16, xor-swizzled
  const float* xb = x + (size_t)b * C * HW + hw0;
  #pragma unroll
  for (int i = 0; i < 16; ++i) {
    int linear = i * 256 + t;
    int p = linear & 127;
    int c4 = (linear >> 7) * 4;
    float a0 = xb[(size_t)(c4 + 0) * HW + p];
    float a1 = xb[(size_t)(c4 + 1) * HW + p];
    float a2 = xb[(size_t)(c4 + 2) * HW + p];
    float a3 = xb[(size_t)(c4 + 3) * HW + p];
    int cc = c4 ^ ((p & 7) << 3);
    *(uint2*)&Xs[p * 128 + cc] = make_uint2(pk2(a0, a1), pk2(a2, a3));
  }
  __syncthreads();

  // coalesced xq emit from staged Xs: [pix][64 dwords]
  #pragma unroll
  for (int i = 0; i < 8; ++i) {
    int linear = i * 256 + t;
    int c8 = (linear & 15) * 8;
    int prow = linear >> 4;
    uint4 v = *(const uint4*)&Xs[prow * 128 + (c8 ^ ((prow & 7) << 3))];
    *(uint4*)&xq[((size_t)(gpix0 + prow)) * 64 + (c8 >> 1)] = v;
  }

  const int wave = t >> 6, lane = t & 63;
  const int wr = wave >> 1, wc = wave & 1;
  const int rsel = lane & 15, quad = lane >> 4;

  f32x4 acc[4][4];
  #pragma unroll
  for (int mi = 0; mi < 4; ++mi)
    #pragma unroll
    for (int ni = 0; ni < 4; ++ni) acc[mi][ni] = (f32x4){0.f, 0.f, 0.f, 0.f};
  #pragma unroll
  for (int ks = 0; ks < 4; ++ks) {
    const int koff = ks * 32 + quad * 8;
    short8 afr[4], bfr[4];
    #pragma unroll
    for (int mi = 0; mi < 4; ++mi) {
      int r = wr * 64 + mi * 16 + rsel;
      afr[mi] = *(const short8*)&Xs[r * 128 + (koff ^ ((r & 7) << 3))];
    }
    #pragma unroll
    for (int ni = 0; ni < 4; ++ni) {
      int r = wc * 64 + ni * 16 + rsel;
      bfr[ni] = *(const short8*)&Mt[r * 128 + (koff ^ ((r & 7) << 3))];  // global, hot
    }
    #pragma unroll
    for (int mi = 0; mi < 4; ++mi)
      #pragma unroll
      for (int ni = 0; ni < 4; ++ni)
        acc[mi][ni] = __builtin_amdgcn_mfma_f32_16x16x32_bf16(afr[mi], bfr[ni], acc[mi][ni], 0, 0, 0);
  }
  __syncthreads();   // all Xs reads done; reuse Xs as q'-tile
  #pragma unroll
  for (int mi = 0; mi < 4; ++mi)
    #pragma unroll
    for (int ni = 0; ni < 4; ++ni)
      #pragma unroll
      for (int r = 0; r < 4; ++r) {
        int p = wr * 64 + mi * 16 + quad * 4 + r;
        int ch = wc * 64 + ni * 16 + rsel;
        Xs[p * 128 + (ch ^ ((p & 7) << 3))] = f2bf1(acc[mi][ni][r]);
      }
  __syncthreads();
  // coalesced qb store
  #pragma unroll
  for (int i = 0; i < 8; ++i) {
    int linear = i * 256 + t;
    int c8 = (linear & 15) * 8;
    int prow = linear >> 4;
    uint4 v = *(const uint4*)&Xs[prow * 128 + (c8 ^ ((prow & 7) << 3))];
    *(uint4*)(qb + (size_t)(gpix0 + prow) * C + c8) = v;
  }
}

// ---------------- Kernel 2: fused gather + attention (bf16, 2 pix/wave) ------
// R6-verified, unchanged (control).
__global__ __launch_bounds__(256) void k_attn(const unsigned short* __restrict__ qb,
                                              const unsigned* __restrict__ xq,
                                              const int* __restrict__ psf,
                                              const int* __restrict__ pwu,
                                              unsigned short* __restrict__ ao) {
  const int t = threadIdx.x;
  const int li = t & 31;
  const int half = (t >> 5) & 1;
  const int gid = blockIdx.x;
  const int b = gid & 3;                         // batch -> XCD spread
  const int grp = gid >> 2;
  const int pixl = (grp << 3) + ((t >> 6) << 1) + half;   // per-lane pixel
  const size_t spix = ((size_t)b << 14) + pixl;

  // scalar tables: pw[0..15], pw[16..31], pi[0..15] (contiguous in workspace)
  v16i w0, w1, tpi;
  asm volatile(
      "s_load_dwordx16 %0, %3, 0\n\t"
      "s_load_dwordx16 %1, %3, 64\n\t"
      "s_load_dwordx16 %2, %3, 128\n\t"
      "s_waitcnt lgkmcnt(0)"
      : "=&s"(w0), "=&s"(w1), "=&s"(tpi)
      : "s"(pwu));

  // per-lane anchor row (uniform within each 32-lane half -> broadcast)
  const int4* pr = (const int4*)(psf + spix * 16);
  int4 a0 = pr[0], a1 = pr[1], a2 = pr[2], a3 = pr[3];
  int va[16] = {a0.x, a0.y, a0.z, a0.w, a1.x, a1.y, a1.z, a1.w,
                a2.x, a2.y, a2.z, a2.w, a3.x, a3.y, a3.z, a3.w};

  // q for my 4 channels
  const uint2 qp = *(const uint2*)((const unsigned*)qb + spix * 64 + 2 * li);
  const float q0 = bflo(qp.x), q1 = bfhi(qp.x);
  const float q2 = bflo(qp.y), q3 = bfhi(qp.y);

  const unsigned* xB = xq + (((size_t)b << 14) << 6);  // batch base (dwords)

  float s0[8], s1[8], s2[8], s3[8], dk[8];
  #pragma unroll
  for (int k = 0; k < 8; ++k) {
    const int x0 = va[2 * k + 0] + tpi[2 * k + 0];
    const int y0 = va[2 * k + 1] + tpi[2 * k + 1];
    float t0 = 0.f, t1 = 0.f, t2 = 0.f, t3 = 0.f;
    #pragma unroll
    for (int cn = 0; cn < 4; ++cn) {
      const int xi = x0 + (cn & 1);
      const int yi = y0 + (cn >> 1);
      const bool valid = ((unsigned)xi <= 127u) & ((unsigned)yi <= 127u);
      const int xc = min(max(xi, 0), 127);   // v_med3_i32
      const int yc = min(max(yi, 0), 127);
      const int widx = k * 4 + cn;
      const float wv = valid ? asf(widx < 16 ? w0[widx & 15] : w1[widx & 15]) : 0.0f;
      const uint2 w2 = *(const uint2*)&xB[((size_t)((yc << 7) + xc) << 6) + 2 * li];
      t0 = fmaf(bflo(w2.x), wv, t0); t1 = fmaf(bfhi(w2.x), wv, t1);
      t2 = fmaf(bflo(w2.y), wv, t2); t3 = fmaf(bfhi(w2.y), wv, t3);
    }
    s0[k] = t0; s1[k] = t1; s2[k] = t2; s3[k] = t3;
    dk[k] = fmaf(q0, t0, fmaf(q1, t1, fmaf(q2, t2, q3 * t3)));
  }
  #pragma unroll
  for (int off = 16; off > 0; off >>= 1) {
    #pragma unroll
    for (int k = 0; k < 8; ++k) dk[k] += __shfl_xor(dk[k], off);
  }
  float m = dk[0];
  #pragma unroll
  for (int k = 1; k < 8; ++k) m = fmaxf(m, dk[k]);
  float den = 0.0f;
  #pragma unroll
  for (int k = 0; k < 8; ++k) { dk[k] = __expf(dk[k] - m); den += dk[k]; }
  const float inv = 1.0f / den;
  float o0 = 0.f, o1 = 0.f, o2 = 0.f, o3 = 0.f;
  #pragma unroll
  for (int k = 0; k < 8; ++k) {
    const float pk = dk[k] * inv;
    o0 = fmaf(pk, s0[k], o0); o1 = fmaf(pk, s1[k], o1);
    o2 = fmaf(pk, s2[k], o2); o3 = fmaf(pk, s3[k], o3);
  }
  *(uint2*)((unsigned*)ao + spix * 64 + 2 * li) = make_uint2(pk2(o0, o1), pk2(o2, o3));
}

// ---------------- Kernel 3: out = bf16(x) + P @ ao  (128-tile) ---------------
// Only As in LDS (32 KB -> 4-5 blocks/CU). Pm fragments direct from global.
// Residual from the bf16 xq copy, re-staged through As after the MFMA loop.
__global__ __launch_bounds__(256) void k_proj(const unsigned short* __restrict__ ao,
                                              const unsigned short* __restrict__ Pm,
                                              const unsigned short* __restrict__ xqh,
                                              float* __restrict__ out) {
  __shared__ __align__(16) unsigned short As[128 * 128];  // 32 KB
  const int t = threadIdx.x;
  const int gpix0 = blockIdx.x * 128;
  const int b = gpix0 >> 14;
  const int hw0 = gpix0 & (HW - 1);

  #pragma unroll
  for (int i = 0; i < 8; ++i) {
    int linear = i * 256 + t;
    int c8 = (linear & 15) * 8;
    int p = linear >> 4;
    uint4 v = *(const uint4*)(ao + (size_t)(gpix0 + p) * C + c8);
    *(uint4*)&As[p * 128 + (c8 ^ ((p & 7) << 3))] = v;
  }
  __syncthreads();

  const int wave = t >> 6, lane = t & 63;
  const int wr = wave >> 1, wc = wave & 1;
  const int rsel = lane & 15, quad = lane >> 4;

  f32x4 acc[4][4];
  #pragma unroll
  for (int mi = 0; mi < 4; ++mi)
    #pragma unroll
    for (int ni = 0; ni < 4; ++ni) acc[mi][ni] = (f32x4){0.f, 0.f, 0.f, 0.f};

  #pragma unroll
  for (int ks = 0; ks < 4; ++ks) {
    const int koff = ks * 32 + quad * 8;
    short8 afr[4], bfr[4];
    #pragma unroll
    for (int mi = 0; mi < 4; ++mi) {
      int r = wr * 64 + mi * 16 + rsel;
      afr[mi] = *(const short8*)&Pm[r * 128 + (koff ^ ((r & 7) << 3))];  // global, hot
    }
    #pragma unroll
    for (int ni = 0; ni < 4; ++ni) {
      int r = wc * 64 + ni * 16 + rsel;
      bfr[ni] = *(const short8*)&As[r * 128 + (koff ^ ((r & 7) << 3))];
    }
    #pragma unroll
    for (int mi = 0; mi < 4; ++mi)
      #pragma unroll
      for (int ni = 0; ni < 4; ++ni)
        acc[mi][ni] = __builtin_amdgcn_mfma_f32_16x16x32_bf16(afr[mi], bfr[ni], acc[mi][ni], 0, 0, 0);
  }

  __syncthreads();   // As MFMA reads done; re-stage As with the x~ tile
  #pragma unroll
  for (int i = 0; i < 8; ++i) {
    int linear = i * 256 + t;
    int c8 = (linear & 15) * 8;
    int p = linear >> 4;
    uint4 v = *(const uint4*)(xqh + (size_t)(gpix0 + p) * C + c8);
    *(uint4*)&As[p * 128 + (c8 ^ ((p & 7) << 3))] = v;
  }
  __syncthreads();

  #pragma unroll
  for (int mi = 0; mi < 4; ++mi)
    #pragma unroll
    for (int ni = 0; ni < 4; ++ni)
      #pragma unroll
      for (int r = 0; r < 4; ++r) {
        int och = wr * 64 + mi * 16 + quad * 4 + r;
        int pixl = wc * 64 + ni * 16 + rsel;
        float xr = bf2f(As[pixl * 128 + (och ^ ((pixl & 7) << 3))]);
        size_t addr = ((size_t)b * C + och) * HW + hw0 + pixl;
        out[addr] = xr + acc[mi][ni][r];
      }
}

extern "C" void kernel_launch(void* const* d_in, const int* in_sizes, int n_in,
                              void* d_out, int out_size, void* d_ws, size_t ws_size,
                              hipStream_t stream) {
  const float* x      = (const float*)d_in[0];
  const int*   psf    = (const int*)d_in[1];
  const float* delta  = (const float*)d_in[2];
  const float* w_qkv  = (const float*)d_in[3];
  const float* w_proj = (const float*)d_in[4];
  float* out = (float*)d_out;

  const size_t N = (size_t)4 * HW * C;                 // 8388608 elems
  unsigned short* qb = (unsigned short*)d_ws;          // 16 MB bf16 q' [pix][ch]
  unsigned short* xq = qb + N;                         // 16 MB bf16 x~ [pix][ch]
  unsigned short* ao = xq + N;                         // 16 MB bf16 out-acc
  unsigned short* Mt = ao + N;                         // 32 KB bf16 swz
  unsigned short* Pm = Mt + 16384;                     // 32 KB bf16 swz
  float* pw = (float*)(Pm + 16384);                    // 32 floats (pi follows)
  int*   pi = (int*)(pw + 32);                         // 16 ints
  (void)pi;

  k_prep<<<dim3(257), 128, 0, stream>>>(w_qkv, w_proj, delta, Mt, Pm, pw, pi);
  k_qx<<<dim3(512), 256, 0, stream>>>(x, Mt, qb, (unsigned*)xq);
  k_attn<<<dim3(8192), 256, 0, stream>>>(qb, (const unsigned*)xq, psf, (const int*)pw, ao);
  k_proj<<<dim3(512), 256, 0, stream>>>(ao, Pm, xq, out);
}